// Round 12
// baseline (739.227 us; speedup 1.0000x reference)
//
#include <hip/hip_runtime.h>
#include <hip/hip_fp16.h>
#include <hip/hip_cooperative_groups.h>

namespace cg = cooperative_groups;

#define N_NODES 50000
#define E_BASE  800000
#define IN_DIM  58
#define HID     100
#define HP2     128            // padded halves per feature row (256 B)
#define SCAN_BLOCKS ((N_NODES + 255) / 256)   // 196
#define CSR_GRID 1024          // cooperative grid: 4 blocks/CU x 256 CUs

// ---- lin1 + relu + fp16 quantize + fused invnorm (computed on quantized vals)
__global__ __launch_bounds__(256) void lin1_kernel(
    const float* __restrict__ x, const float* __restrict__ w,
    const float* __restrict__ b, __half* __restrict__ h,
    float* __restrict__ invn) {
  __shared__ alignas(16) float xs[64 * IN_DIM];    // [n][k] linear
  __shared__ alignas(16) float wsm[IN_DIM * HP2];  // [k][j], cols >=100 zero
  __shared__ float bl[HP2];
  int tid = threadIdx.x;
  int nb = blockIdx.x * 64;
  for (int i = tid; i < 64 * IN_DIM; i += 256) {
    int g = nb * IN_DIM + i;
    xs[i] = (g < N_NODES * IN_DIM) ? x[g] : 0.f;
  }
  for (int i = tid; i < IN_DIM * HP2; i += 256) {
    int k = i / HP2, j = i - k * HP2;
    wsm[i] = (j < HID) ? w[j * IN_DIM + k] : 0.f;
  }
  if (tid < HP2) bl[tid] = (tid < HID) ? b[tid] : 0.f;
  __syncthreads();
  int t_j = tid & 15, t_n = tid >> 4;
  float acc[4][8];
#pragma unroll
  for (int ni = 0; ni < 4; ++ni)
#pragma unroll
    for (int j = 0; j < 8; ++j) acc[ni][j] = bl[8 * t_j + j];
  for (int k = 0; k < IN_DIM; ++k) {
    float xv[4];
#pragma unroll
    for (int ni = 0; ni < 4; ++ni) xv[ni] = xs[(4 * t_n + ni) * IN_DIM + k];
    float4 wa = *(const float4*)&wsm[k * HP2 + 8 * t_j];
    float4 wb = *(const float4*)&wsm[k * HP2 + 8 * t_j + 4];
    float wv[8] = {wa.x, wa.y, wa.z, wa.w, wb.x, wb.y, wb.z, wb.w};
#pragma unroll
    for (int ni = 0; ni < 4; ++ni)
#pragma unroll
      for (int j = 0; j < 8; ++j) acc[ni][j] = fmaf(xv[ni], wv[j], acc[ni][j]);
  }
#pragma unroll
  for (int ni = 0; ni < 4; ++ni) {
    int n = nb + 4 * t_n + ni;
    uint4 st;
    ushort* sp = (ushort*)&st;
    float ss = 0.f;
#pragma unroll
    for (int j = 0; j < 8; ++j) {
      float v = fmaxf(acc[ni][j], 0.f);
      __half hv = __float2half_rn(v);
      sp[j] = __half_as_ushort(hv);
      float vq = __half2float(hv);
      ss = fmaf(vq, vq, ss);
    }
#pragma unroll
    for (int off = 1; off < 16; off <<= 1) ss += __shfl_xor(ss, off);
    if (n < N_NODES) {
      *((uint4*)(h + (size_t)n * HP2) + t_j) = st;
      if (t_j == 0) invn[n] = 1.f / fmaxf(sqrtf(ss), 1e-12f);
    }
  }
}

// ---- single cooperative kernel: zero-deg -> hist(+rank) -> scan -> scatter
// rank[e] = atomicAdd old value = slot of edge e within its dst row (plus 1
// for the self loop in slot 0) -> scatter needs NO atomics.
__global__ __launch_bounds__(256) void build_csr_kernel(
    const int* __restrict__ ei, int* __restrict__ deg, int* __restrict__ rank,
    int* __restrict__ blocksum, int* __restrict__ rowstart,
    int* __restrict__ src_csr) {
  cg::grid_group grid = cg::this_grid();
  __shared__ int sh[256];
  __shared__ int top[256];
  int tid = threadIdx.x;
  int gtid = blockIdx.x * 256 + tid;
  const int nthreads = CSR_GRID * 256;

  // phase 0: zero the degree array
  for (int i = gtid; i < N_NODES; i += nthreads) deg[i] = 0;
  grid.sync();

  // phase 1: histogram + within-row rank capture (4 edges/thread-iter)
  for (int i = gtid; i < E_BASE / 4; i += nthreads) {
    int4 d4 = ((const int4*)(ei + E_BASE))[i];
    int r0 = atomicAdd(&deg[d4.x], 1);
    int r1 = atomicAdd(&deg[d4.y], 1);
    int r2 = atomicAdd(&deg[d4.z], 1);
    int r3 = atomicAdd(&deg[d4.w], 1);
    ((int4*)rank)[i] = make_int4(r0, r1, r2, r3);
  }
  grid.sync();

  // phase 2a: per-block partial sums of (deg+1) for blocks < SCAN_BLOCKS
  if (blockIdx.x < SCAN_BLOCKS) {
    int idx = blockIdx.x * 256 + tid;
    int v = (idx < N_NODES) ? deg[idx] + 1 : 0;
#pragma unroll
    for (int off = 32; off; off >>= 1) v += __shfl_xor(v, off);
    if (tid == 0) sh[0] = v;
    if (tid == 64) sh[1] = v;
    if (tid == 128) sh[2] = v;
    if (tid == 192) sh[3] = v;
    __syncthreads();
    if (tid == 0) blocksum[blockIdx.x] = sh[0] + sh[1] + sh[2] + sh[3];
  }
  grid.sync();

  // phase 2b: block 0 exclusive-scans the block sums in LDS
  if (blockIdx.x == 0) {
    top[tid] = (tid < SCAN_BLOCKS) ? blocksum[tid] : 0;
    __syncthreads();
    for (int off = 1; off < 256; off <<= 1) {
      int v = (tid >= off) ? top[tid - off] : 0;
      __syncthreads();
      top[tid] += v;
      __syncthreads();
    }
    if (tid < SCAN_BLOCKS) blocksum[tid] = (tid == 0) ? 0 : top[tid - 1];
  }
  grid.sync();

  // phase 2c: block-local scan + offset -> rowstart + self-loop slot 0
  if (blockIdx.x < SCAN_BLOCKS) {
    int idx = blockIdx.x * 256 + tid;
    int v = (idx < N_NODES) ? deg[idx] + 1 : 0;
    sh[tid] = v;
    __syncthreads();
    for (int off = 1; off < 256; off <<= 1) {
      int u = (tid >= off) ? sh[tid - off] : 0;
      __syncthreads();
      sh[tid] += u;
      __syncthreads();
    }
    int excl = blocksum[blockIdx.x] + sh[tid] - v;
    if (idx < N_NODES) {
      rowstart[idx] = excl;
      src_csr[excl] = idx;      // self loop in slot 0, no atomic
    }
    if (idx == N_NODES - 1) rowstart[N_NODES] = excl + v;
  }
  grid.sync();

  // phase 3: scatter base edges, atomic-free via rank
  for (int i = gtid; i < E_BASE / 4; i += nthreads) {
    int4 s4 = ((const int4*)ei)[i];
    int4 d4 = ((const int4*)(ei + E_BASE))[i];
    int4 r4 = ((const int4*)rank)[i];
    src_csr[rowstart[d4.x] + 1 + r4.x] = s4.x;
    src_csr[rowstart[d4.y] + 1 + r4.y] = s4.y;
    src_csr[rowstart[d4.z] + 1 + r4.z] = s4.z;
    src_csr[rowstart[d4.w] + 1 + r4.w] = s4.w;
  }
}

// ---------------------------------------------------------------- fused prop
// One wave per node; 4 edges in parallel (16-lane quarters). fp16 rows, one
// dwordx4 per lane per row. Softmax max FIXED at B=|beta| (logits bounded);
// quarter states merge by plain addition. (Round-9 form: best measured.)
template<bool WRITE_INVN, bool FINAL>
__global__ __launch_bounds__(256) void prop_kernel(
    const __half* __restrict__ h, const float* __restrict__ invn,
    const int* __restrict__ src_csr, const int* __restrict__ rowstart,
    const float* __restrict__ beta_ptr,
    __half* __restrict__ out_feat, float* __restrict__ out_invn,
    const float* __restrict__ w2, const float* __restrict__ b2,
    float* __restrict__ out_scalar) {
  int node = (blockIdx.x * 256 + threadIdx.x) >> 6;
  int lane = threadIdx.x & 63;
  if (node >= N_NODES) return;
  int lq = lane & 15, q = lane >> 4;
  float beta = beta_ptr ? beta_ptr[0] : 1.0f;
  float B = fabsf(beta);
  int start = rowstart[node], end = rowstart[node + 1];
  int deg = end - start;               // >= 1 (self loop)
  float ind = invn[node];
  uint4 dv = *((const uint4*)(h + (size_t)node * HP2) + lq);
  const __half* dh = (const __half*)&dv;
  float d[8];
#pragma unroll
  for (int j = 0; j < 8; ++j) d[j] = __half2float(dh[j]) * ind;
  float s = 0.f;
  float acc[8];
#pragma unroll
  for (int j = 0; j < 8; ++j) acc[j] = 0.f;
  int nt = (deg + 3) >> 2;
  for (int r = 0; r < nt; ++r) {
    int e = 4 * r + q;
    bool valid = e < deg;
    int p = start + (valid ? e : 0);
    int sn = src_csr[p];
    float iv = invn[sn];
    uint4 vv = *((const uint4*)(h + (size_t)sn * HP2) + lq);
    const __half* vh = (const __half*)&vv;
    float vf[8];
#pragma unroll
    for (int j = 0; j < 8; ++j) vf[j] = __half2float(vh[j]);
    float t = 0.f;
#pragma unroll
    for (int j = 0; j < 8; ++j) t = fmaf(vf[j], d[j], t);
#pragma unroll
    for (int off = 8; off; off >>= 1) t += __shfl_xor(t, off);
    float a = valid ? beta * t * iv : -1e30f;
    float wgt = __expf(a - B);         // in (0, ~1]; 0 for invalid slots
    s += wgt;
#pragma unroll
    for (int j = 0; j < 8; ++j) acc[j] = fmaf(wgt, vf[j], acc[j]);
  }
  // merge the 4 quarter states: plain sums (shared fixed max B)
#pragma unroll
  for (int off = 16; off <= 32; off <<= 1) {
    s += __shfl_xor(s, off);
#pragma unroll
    for (int j = 0; j < 8; ++j) acc[j] += __shfl_xor(acc[j], off);
  }
  float invden = 1.f / (s + 1e-16f);
  if (!FINAL) {
    uint4 st;
    ushort* sp = (ushort*)&st;
    float ss = 0.f;
#pragma unroll
    for (int j = 0; j < 8; ++j) {
      __half hv = __float2half_rn(acc[j] * invden);
      sp[j] = __half_as_ushort(hv);
      float vq = __half2float(hv);
      ss = fmaf(vq, vq, ss);
    }
    if (q == 0) *((uint4*)(out_feat + (size_t)node * HP2) + lq) = st;
    if (WRITE_INVN) {
#pragma unroll
      for (int off = 1; off < 16; off <<= 1) ss += __shfl_xor(ss, off);
      if (lane == 0) out_invn[node] = 1.f / fmaxf(sqrtf(ss), 1e-12f);
    }
  } else {
    float qq = 0.f;
#pragma unroll
    for (int j = 0; j < 8; ++j) {
      int f = 8 * lq + j;
      float wv = (f < HID) ? w2[f] : 0.f;
      qq = fmaf(acc[j] * invden, wv, qq);
    }
#pragma unroll
    for (int off = 8; off; off >>= 1) qq += __shfl_xor(qq, off);
    if (lane == 0) out_scalar[node] = qq + b2[0];
  }
}

extern "C" void kernel_launch(void* const* d_in, const int* in_sizes, int n_in,
                              void* d_out, int out_size, void* d_ws, size_t ws_size,
                              hipStream_t stream) {
  const float* x      = (const float*)d_in[0];
  const int*   ei     = (const int*)d_in[1];     // [2][E_BASE], int32
  const float* lin1_w = (const float*)d_in[2];
  const float* lin1_b = (const float*)d_in[3];
  const float* beta2  = (const float*)d_in[4];
  const float* lin2_w = (const float*)d_in[5];
  const float* lin2_b = (const float*)d_in[6];
  float* out = (float*)d_out;

  // workspace layout (16B-aligned sections first)
  char* wsb = (char*)d_ws;
  __half* h1 = (__half*)wsb;                       wsb += (size_t)N_NODES * HP2 * 2;
  __half* h2 = (__half*)wsb;                       wsb += (size_t)N_NODES * HP2 * 2;
  float* invn1 = (float*)wsb;                      wsb += N_NODES * 4;
  float* invn2 = (float*)wsb;                      wsb += N_NODES * 4;
  int* deg      = (int*)wsb;                       wsb += N_NODES * 4;
  int* rank     = (int*)wsb;                       wsb += (size_t)E_BASE * 4;
  int* blocksum = (int*)wsb;                       wsb += 256 * 4;
  int* rowstart = (int*)wsb;                       wsb += (N_NODES + 1) * 4;
  int* src_csr  = (int*)wsb;                       wsb += (size_t)(E_BASE + N_NODES) * 4;

  // ---- lin1 + relu -> fp16 h1 + invn1 (fused)
  lin1_kernel<<<(N_NODES + 63) / 64, 256, 0, stream>>>(x, lin1_w, lin1_b, h1, invn1);

  // ---- build CSR in ONE cooperative kernel (5 phases, 5 grid syncs)
  {
    const int* ei_a = ei;
    int* deg_a = deg; int* rank_a = rank; int* bs_a = blocksum;
    int* rs_a = rowstart; int* sc_a = src_csr;
    void* args[] = {(void*)&ei_a, (void*)&deg_a, (void*)&rank_a,
                    (void*)&bs_a, (void*)&rs_a, (void*)&sc_a};
    hipLaunchCooperativeKernel((void*)build_csr_kernel, dim3(CSR_GRID),
                               dim3(256), args, 0, stream);
  }

  // ---- prop 1 (beta = 1.0): h1 -> h2 (fp16) + invn2 (fused)
  prop_kernel<true, false><<<(N_NODES + 3) / 4, 256, 0, stream>>>(
      h1, invn1, src_csr, rowstart, nullptr, h2, invn2, nullptr, nullptr, nullptr);

  // ---- prop 2 (beta = beta2[0]) fused with lin2: h2 -> out (scalar per node)
  prop_kernel<false, true><<<(N_NODES + 3) / 4, 256, 0, stream>>>(
      h2, invn2, src_csr, rowstart, beta2, nullptr, nullptr, lin2_w, lin2_b, out);
}

// Round 13
// 263.623 us; speedup vs baseline: 2.8041x; 2.8041x over previous
//
#include <hip/hip_runtime.h>
#include <hip/hip_fp16.h>

#define N_NODES 50000
#define E_BASE  800000
#define IN_DIM  58
#define HID     100
#define HP2     128            // padded halves per feature row (256 B)
#define SCAN_BLOCKS ((N_NODES + 255) / 256)   // 196

// ---- lin1 + relu + fp16 quantize + fused invnorm; also zeroes deg[] for the
// downstream histogram (stream order guarantees completion before hist runs).
__global__ __launch_bounds__(256) void lin1_kernel(
    const float* __restrict__ x, const float* __restrict__ w,
    const float* __restrict__ b, __half* __restrict__ h,
    float* __restrict__ invn, int* __restrict__ deg) {
  __shared__ alignas(16) float xs[64 * IN_DIM];    // [n][k] linear
  __shared__ alignas(16) float wsm[IN_DIM * HP2];  // [k][j], cols >=100 zero
  __shared__ float bl[HP2];
  int tid = threadIdx.x;
  int nb = blockIdx.x * 64;
  // zero deg with spare parallelism (grid = 782 blocks x 256 = 200k threads)
  int gtid = blockIdx.x * 256 + tid;
  if (gtid < N_NODES) deg[gtid] = 0;
  for (int i = tid; i < 64 * IN_DIM; i += 256) {
    int g = nb * IN_DIM + i;
    xs[i] = (g < N_NODES * IN_DIM) ? x[g] : 0.f;
  }
  for (int i = tid; i < IN_DIM * HP2; i += 256) {
    int k = i / HP2, j = i - k * HP2;
    wsm[i] = (j < HID) ? w[j * IN_DIM + k] : 0.f;
  }
  if (tid < HP2) bl[tid] = (tid < HID) ? b[tid] : 0.f;
  __syncthreads();
  int t_j = tid & 15, t_n = tid >> 4;
  float acc[4][8];
#pragma unroll
  for (int ni = 0; ni < 4; ++ni)
#pragma unroll
    for (int j = 0; j < 8; ++j) acc[ni][j] = bl[8 * t_j + j];
  for (int k = 0; k < IN_DIM; ++k) {
    float xv[4];
#pragma unroll
    for (int ni = 0; ni < 4; ++ni) xv[ni] = xs[(4 * t_n + ni) * IN_DIM + k];
    float4 wa = *(const float4*)&wsm[k * HP2 + 8 * t_j];
    float4 wb = *(const float4*)&wsm[k * HP2 + 8 * t_j + 4];
    float wv[8] = {wa.x, wa.y, wa.z, wa.w, wb.x, wb.y, wb.z, wb.w};
#pragma unroll
    for (int ni = 0; ni < 4; ++ni)
#pragma unroll
      for (int j = 0; j < 8; ++j) acc[ni][j] = fmaf(xv[ni], wv[j], acc[ni][j]);
  }
#pragma unroll
  for (int ni = 0; ni < 4; ++ni) {
    int n = nb + 4 * t_n + ni;
    uint4 st;
    ushort* sp = (ushort*)&st;
    float ss = 0.f;
#pragma unroll
    for (int j = 0; j < 8; ++j) {
      float v = fmaxf(acc[ni][j], 0.f);
      __half hv = __float2half_rn(v);
      sp[j] = __half_as_ushort(hv);
      float vq = __half2float(hv);
      ss = fmaf(vq, vq, ss);
    }
#pragma unroll
    for (int off = 1; off < 16; off <<= 1) ss += __shfl_xor(ss, off);
    if (n < N_NODES) {
      *((uint4*)(h + (size_t)n * HP2) + t_j) = st;
      if (t_j == 0) invn[n] = 1.f / fmaxf(sqrtf(ss), 1e-12f);
    }
  }
}

// --------- in-degree histogram + within-row rank capture (4 edges/thread)
// rank[e] = old count = slot of edge e within its dst row (before +1 shift
// for the self loop) -> scatter becomes atomic-free.
__global__ __launch_bounds__(256) void hist_kernel(
    const int* __restrict__ ei, int* __restrict__ deg, int* __restrict__ rank) {
  int i = blockIdx.x * 256 + threadIdx.x;
  if (i >= E_BASE / 4) return;
  int4 d4 = ((const int4*)(ei + E_BASE))[i];
  int r0 = atomicAdd(&deg[d4.x], 1);
  int r1 = atomicAdd(&deg[d4.y], 1);
  int r2 = atomicAdd(&deg[d4.z], 1);
  int r3 = atomicAdd(&deg[d4.w], 1);
  ((int4*)rank)[i] = make_int4(r0, r1, r2, r3);
}

// ------------------------------------------- hierarchical scan: block partials
// counts are deg[idx]+1 (implicit self loop)
__global__ __launch_bounds__(256) void scan_blocks_kernel(
    const int* __restrict__ deg, int* __restrict__ blocksum) {
  __shared__ int sh[4];
  int idx = blockIdx.x * 256 + threadIdx.x;
  int v = (idx < N_NODES) ? deg[idx] + 1 : 0;
#pragma unroll
  for (int off = 32; off; off >>= 1) v += __shfl_xor(v, off);
  if ((threadIdx.x & 63) == 0) sh[threadIdx.x >> 6] = v;
  __syncthreads();
  if (threadIdx.x == 0) blocksum[blockIdx.x] = sh[0] + sh[1] + sh[2] + sh[3];
}

// ---- scan apply with INTEGRATED top scan (each block redundantly scans the
// 196 block sums in LDS, sharing the same barriers as the per-element scan).
// Writes rowstart and the self-loop edge into slot 0.
__global__ __launch_bounds__(256) void scan_apply_kernel(
    const int* __restrict__ deg, const int* __restrict__ blocksum,
    int* __restrict__ rowstart, int* __restrict__ src_csr) {
  __shared__ int top[256];
  __shared__ int sh[256];
  int t = threadIdx.x;
  int idx = blockIdx.x * 256 + t;
  top[t] = (t < SCAN_BLOCKS) ? blocksum[t] : 0;
  int v = (idx < N_NODES) ? deg[idx] + 1 : 0;
  sh[t] = v;
  __syncthreads();
  for (int off = 1; off < 256; off <<= 1) {
    int a = (t >= off) ? top[t - off] : 0;
    int b = (t >= off) ? sh[t - off] : 0;
    __syncthreads();
    top[t] += a;
    sh[t] += b;
    __syncthreads();
  }
  int blockoff = (blockIdx.x == 0) ? 0 : top[blockIdx.x - 1];
  int excl = blockoff + sh[t] - v;
  if (idx < N_NODES) {
    rowstart[idx] = excl;
    src_csr[excl] = idx;      // self loop occupies slot 0, no atomic
  }
  if (idx == N_NODES - 1) rowstart[N_NODES] = excl + v;
}

// ------------- scatter base edges into CSR, ATOMIC-FREE via captured rank
__global__ __launch_bounds__(256) void scatter_kernel(
    const int* __restrict__ ei, const int* __restrict__ rowstart,
    const int* __restrict__ rank, int* __restrict__ src_csr) {
  int i = blockIdx.x * 256 + threadIdx.x;
  if (i >= E_BASE / 4) return;
  int4 s4 = ((const int4*)ei)[i];
  int4 d4 = ((const int4*)(ei + E_BASE))[i];
  int4 r4 = ((const int4*)rank)[i];
  src_csr[rowstart[d4.x] + 1 + r4.x] = s4.x;
  src_csr[rowstart[d4.y] + 1 + r4.y] = s4.y;
  src_csr[rowstart[d4.z] + 1 + r4.z] = s4.z;
  src_csr[rowstart[d4.w] + 1 + r4.w] = s4.w;
}

// ---------------------------------------------------------------- fused prop
// One wave per node; 4 edges in parallel (16-lane quarters). fp16 rows, one
// dwordx4 per lane per row. Softmax max FIXED at B=|beta| (logits bounded);
// quarter states merge by plain addition. (Round-9 form: best measured.)
template<bool WRITE_INVN, bool FINAL>
__global__ __launch_bounds__(256) void prop_kernel(
    const __half* __restrict__ h, const float* __restrict__ invn,
    const int* __restrict__ src_csr, const int* __restrict__ rowstart,
    const float* __restrict__ beta_ptr,
    __half* __restrict__ out_feat, float* __restrict__ out_invn,
    const float* __restrict__ w2, const float* __restrict__ b2,
    float* __restrict__ out_scalar) {
  int node = (blockIdx.x * 256 + threadIdx.x) >> 6;
  int lane = threadIdx.x & 63;
  if (node >= N_NODES) return;
  int lq = lane & 15, q = lane >> 4;
  float beta = beta_ptr ? beta_ptr[0] : 1.0f;
  float B = fabsf(beta);
  int start = rowstart[node], end = rowstart[node + 1];
  int deg = end - start;               // >= 1 (self loop)
  float ind = invn[node];
  uint4 dv = *((const uint4*)(h + (size_t)node * HP2) + lq);
  const __half* dh = (const __half*)&dv;
  float d[8];
#pragma unroll
  for (int j = 0; j < 8; ++j) d[j] = __half2float(dh[j]) * ind;
  float s = 0.f;
  float acc[8];
#pragma unroll
  for (int j = 0; j < 8; ++j) acc[j] = 0.f;
  int nt = (deg + 3) >> 2;
  for (int r = 0; r < nt; ++r) {
    int e = 4 * r + q;
    bool valid = e < deg;
    int p = start + (valid ? e : 0);
    int sn = src_csr[p];
    float iv = invn[sn];
    uint4 vv = *((const uint4*)(h + (size_t)sn * HP2) + lq);
    const __half* vh = (const __half*)&vv;
    float vf[8];
#pragma unroll
    for (int j = 0; j < 8; ++j) vf[j] = __half2float(vh[j]);
    float t = 0.f;
#pragma unroll
    for (int j = 0; j < 8; ++j) t = fmaf(vf[j], d[j], t);
#pragma unroll
    for (int off = 8; off; off >>= 1) t += __shfl_xor(t, off);
    float a = valid ? beta * t * iv : -1e30f;
    float wgt = __expf(a - B);         // in (0, ~1]; 0 for invalid slots
    s += wgt;
#pragma unroll
    for (int j = 0; j < 8; ++j) acc[j] = fmaf(wgt, vf[j], acc[j]);
  }
  // merge the 4 quarter states: plain sums (shared fixed max B)
#pragma unroll
  for (int off = 16; off <= 32; off <<= 1) {
    s += __shfl_xor(s, off);
#pragma unroll
    for (int j = 0; j < 8; ++j) acc[j] += __shfl_xor(acc[j], off);
  }
  float invden = 1.f / (s + 1e-16f);
  if (!FINAL) {
    uint4 st;
    ushort* sp = (ushort*)&st;
    float ss = 0.f;
#pragma unroll
    for (int j = 0; j < 8; ++j) {
      __half hv = __float2half_rn(acc[j] * invden);
      sp[j] = __half_as_ushort(hv);
      float vq = __half2float(hv);
      ss = fmaf(vq, vq, ss);
    }
    if (q == 0) *((uint4*)(out_feat + (size_t)node * HP2) + lq) = st;
    if (WRITE_INVN) {
#pragma unroll
      for (int off = 1; off < 16; off <<= 1) ss += __shfl_xor(ss, off);
      if (lane == 0) out_invn[node] = 1.f / fmaxf(sqrtf(ss), 1e-12f);
    }
  } else {
    float qq = 0.f;
#pragma unroll
    for (int j = 0; j < 8; ++j) {
      int f = 8 * lq + j;
      float wv = (f < HID) ? w2[f] : 0.f;
      qq = fmaf(acc[j] * invden, wv, qq);
    }
#pragma unroll
    for (int off = 8; off; off >>= 1) qq += __shfl_xor(qq, off);
    if (lane == 0) out_scalar[node] = qq + b2[0];
  }
}

extern "C" void kernel_launch(void* const* d_in, const int* in_sizes, int n_in,
                              void* d_out, int out_size, void* d_ws, size_t ws_size,
                              hipStream_t stream) {
  const float* x      = (const float*)d_in[0];
  const int*   ei     = (const int*)d_in[1];     // [2][E_BASE], int32
  const float* lin1_w = (const float*)d_in[2];
  const float* lin1_b = (const float*)d_in[3];
  const float* beta2  = (const float*)d_in[4];
  const float* lin2_w = (const float*)d_in[5];
  const float* lin2_b = (const float*)d_in[6];
  float* out = (float*)d_out;

  // workspace layout (16B-aligned sections first)
  char* wsb = (char*)d_ws;
  __half* h1 = (__half*)wsb;                       wsb += (size_t)N_NODES * HP2 * 2;
  __half* h2 = (__half*)wsb;                       wsb += (size_t)N_NODES * HP2 * 2;
  float* invn1 = (float*)wsb;                      wsb += N_NODES * 4;
  float* invn2 = (float*)wsb;                      wsb += N_NODES * 4;
  int* deg      = (int*)wsb;                       wsb += N_NODES * 4;
  int* rank     = (int*)wsb;                       wsb += (size_t)E_BASE * 4;
  int* blocksum = (int*)wsb;                       wsb += 256 * 4;
  int* rowstart = (int*)wsb;                       wsb += (N_NODES + 1) * 4;
  int* src_csr  = (int*)wsb;                       wsb += (size_t)(E_BASE + N_NODES) * 4;

  // ---- lin1 + relu -> fp16 h1 + invn1 (fused) + deg zeroing
  lin1_kernel<<<(N_NODES + 63) / 64, 256, 0, stream>>>(x, lin1_w, lin1_b, h1, invn1, deg);

  // ---- build CSR by dst: hist(+rank) -> scan -> apply -> atomic-free scatter
  hist_kernel<<<(E_BASE / 4 + 255) / 256, 256, 0, stream>>>(ei, deg, rank);
  scan_blocks_kernel<<<SCAN_BLOCKS, 256, 0, stream>>>(deg, blocksum);
  scan_apply_kernel<<<SCAN_BLOCKS, 256, 0, stream>>>(deg, blocksum, rowstart, src_csr);
  scatter_kernel<<<(E_BASE / 4 + 255) / 256, 256, 0, stream>>>(ei, rowstart, rank, src_csr);

  // ---- prop 1 (beta = 1.0): h1 -> h2 (fp16) + invn2 (fused)
  prop_kernel<true, false><<<(N_NODES + 3) / 4, 256, 0, stream>>>(
      h1, invn1, src_csr, rowstart, nullptr, h2, invn2, nullptr, nullptr, nullptr);

  // ---- prop 2 (beta = beta2[0]) fused with lin2: h2 -> out (scalar per node)
  prop_kernel<false, true><<<(N_NODES + 3) / 4, 256, 0, stream>>>(
      h2, invn2, src_csr, rowstart, beta2, nullptr, nullptr, lin2_w, lin2_b, out);
}